// Round 1
// baseline (873.731 us; speedup 1.0000x reference)
//
#include <hip/hip_runtime.h>
#include <hip/hip_bf16.h>
#include <math.h>

// Problem constants
#define B_  1
#define S_  512
#define D_  2048
#define HK_ 8
#define HV_ 16
#define DK_ 128
#define DV_ 128
#define KC_ 4          // conv kernel size
#define R_  2          // HV/HK
#define KEY_DIM_ 1024
#define VAL_DIM_ 2048
#define QKVZ_N  6144   // 2*KEY_DIM + 2*VAL_DIM
#define EPS_ 1e-6f

// ---------------------------------------------------------------------------
// fp32 tiled GEMM: C[M,N] = A[M,K] @ B[K,N], all row-major. M,N multiples of 64,
// K multiple of 16.
// ---------------------------------------------------------------------------
#define TILE 64
#define BK   16

__global__ __launch_bounds__(256) void gemm_f32(const float* __restrict__ A,
                                                const float* __restrict__ Bm,
                                                float* __restrict__ C,
                                                int M, int N, int K) {
    __shared__ float As[BK][TILE];   // As[k][m]
    __shared__ float Bs[BK][TILE];   // Bs[k][n]

    const int t   = threadIdx.x;
    const int tx4 = (t % 16) * 4;    // n-dir micro tile
    const int ty4 = (t / 16) * 4;    // m-dir micro tile
    const int m0  = blockIdx.y * TILE;
    const int n0  = blockIdx.x * TILE;

    // loader indices
    const int arow = t / 4;          // 0..63
    const int acol = (t % 4) * 4;    // 0,4,8,12
    const int brow = t / 16;         // 0..15
    const int bcol = (t % 16) * 4;   // 0..60

    float acc[4][4] = {};

    for (int k0 = 0; k0 < K; k0 += BK) {
        float4 av = *(const float4*)&A[(size_t)(m0 + arow) * K + k0 + acol];
        float4 bv = *(const float4*)&Bm[(size_t)(k0 + brow) * N + n0 + bcol];
        __syncthreads();   // previous iteration's compute done before overwrite
        As[acol + 0][arow] = av.x;
        As[acol + 1][arow] = av.y;
        As[acol + 2][arow] = av.z;
        As[acol + 3][arow] = av.w;
        *(float4*)&Bs[brow][bcol] = bv;
        __syncthreads();
#pragma unroll
        for (int kk = 0; kk < BK; ++kk) {
            float a0 = As[kk][ty4 + 0], a1 = As[kk][ty4 + 1];
            float a2 = As[kk][ty4 + 2], a3 = As[kk][ty4 + 3];
            float b0 = Bs[kk][tx4 + 0], b1 = Bs[kk][tx4 + 1];
            float b2 = Bs[kk][tx4 + 2], b3 = Bs[kk][tx4 + 3];
            acc[0][0] += a0 * b0; acc[0][1] += a0 * b1; acc[0][2] += a0 * b2; acc[0][3] += a0 * b3;
            acc[1][0] += a1 * b0; acc[1][1] += a1 * b1; acc[1][2] += a1 * b2; acc[1][3] += a1 * b3;
            acc[2][0] += a2 * b0; acc[2][1] += a2 * b1; acc[2][2] += a2 * b2; acc[2][3] += a2 * b3;
            acc[3][0] += a3 * b0; acc[3][1] += a3 * b1; acc[3][2] += a3 * b2; acc[3][3] += a3 * b3;
        }
    }
#pragma unroll
    for (int i = 0; i < 4; ++i) {
        float4 r = make_float4(acc[i][0], acc[i][1], acc[i][2], acc[i][3]);
        *(float4*)&C[(size_t)(m0 + ty4 + i) * N + n0 + tx4] = r;
    }
}

// ---------------------------------------------------------------------------
// ba = hidden @ W_ba  (512x2048 @ 2048x32)
// ---------------------------------------------------------------------------
__global__ __launch_bounds__(256) void ba_kernel(const float* __restrict__ hid,
                                                 const float* __restrict__ Wba,
                                                 float* __restrict__ ba) {
    int id = blockIdx.x * blockDim.x + threadIdx.x;  // 0 .. 512*32-1
    if (id >= S_ * 32) return;
    int s = id >> 5;
    int j = id & 31;
    float sum = 0.f;
    const float* hrow = hid + (size_t)s * D_;
#pragma unroll 8
    for (int k = 0; k < D_; ++k) {
        sum += hrow[k] * Wba[(size_t)k * 32 + j];
    }
    ba[id] = sum;
}

// ---------------------------------------------------------------------------
// causal depthwise conv (K=4) + silu, then l2norm for q/k groups.
// grid: (S, 32) ; block 128.   groups: 0-7 q heads, 8-15 k heads, 16-31 v heads
// ---------------------------------------------------------------------------
__global__ __launch_bounds__(128) void conv_kernel(const float* __restrict__ qkvz,
                                                   const float* __restrict__ conv_w,
                                                   float* __restrict__ qc,
                                                   float* __restrict__ kc,
                                                   float* __restrict__ vc) {
    const int s   = blockIdx.x;
    const int grp = blockIdx.y;
    const int d   = threadIdx.x;   // 0..127

    int col, c;   // col: column in qkvz row; c: conv channel
    if (grp < 8) {                       // q, head hk = grp
        int hk = grp;
        col = hk * 768 + d;
        c   = hk * 128 + d;
    } else if (grp < 16) {               // k, head hk = grp-8
        int hk = grp - 8;
        col = hk * 768 + 128 + d;
        c   = 1024 + (hk * 128 + d);
    } else {                             // v, head hv = grp-16
        int hv = grp - 16;
        col = (hv >> 1) * 768 + 256 + (hv & 1) * 128 + d;
        c   = 2048 + (hv * 128 + d);
    }

    const float w0 = conv_w[c * 4 + 0];
    const float w1 = conv_w[c * 4 + 1];
    const float w2 = conv_w[c * 4 + 2];
    const float w3 = conv_w[c * 4 + 3];

    float x = 0.f;
    if (s - 3 >= 0) x += qkvz[(size_t)(s - 3) * QKVZ_N + col] * w0;
    if (s - 2 >= 0) x += qkvz[(size_t)(s - 2) * QKVZ_N + col] * w1;
    if (s - 1 >= 0) x += qkvz[(size_t)(s - 1) * QKVZ_N + col] * w2;
    x += qkvz[(size_t)s * QKVZ_N + col] * w3;

    // silu
    x = x / (1.f + expf(-x));

    if (grp < 16) {
        // l2 norm over the 128-wide head dim (sum of squares, not mean)
        float ss = x * x;
#pragma unroll
        for (int m = 1; m < 64; m <<= 1) ss += __shfl_xor(ss, m);
        __shared__ float red[2];
        int wid = threadIdx.x >> 6;
        if ((threadIdx.x & 63) == 0) red[wid] = ss;
        __syncthreads();
        float tot = red[0] + red[1];
        float scale = rsqrtf(tot + EPS_);
        if (grp < 8) {
            x = x * scale * 0.08838834764831845f;  // * DK^-0.5
            qc[((size_t)s * HK_ + grp) * DK_ + d] = x;
        } else {
            x = x * scale;
            kc[((size_t)s * HK_ + (grp - 8)) * DK_ + d] = x;
        }
    } else {
        vc[((size_t)s * HV_ + (grp - 16)) * DV_ + d] = x;
    }
}

// ---------------------------------------------------------------------------
// gating: beta = sigmoid(b), g = exp(-exp(A_log) * softplus(a + dt_bias))
// ---------------------------------------------------------------------------
__global__ __launch_bounds__(256) void gating_kernel(const float* __restrict__ ba,
                                                     const float* __restrict__ A_log,
                                                     const float* __restrict__ dt_bias,
                                                     float* __restrict__ g,
                                                     float* __restrict__ beta) {
    int id = blockIdx.x * blockDim.x + threadIdx.x;  // 0 .. 512*16-1
    if (id >= S_ * HV_) return;
    int s  = id >> 4;
    int hv = id & 15;
    int hk = hv >> 1;
    int r  = hv & 1;
    float b = ba[s * 32 + hk * 4 + r];
    float a = ba[s * 32 + hk * 4 + 2 + r];
    beta[id] = 1.f / (1.f + expf(-b));
    float x  = a + dt_bias[hv];
    float sp = (x > 20.f) ? x : log1pf(expf(x));
    g[id] = expf(-expf(A_log[hv]) * sp);
}

// ---------------------------------------------------------------------------
// gated delta-rule scan. State columns are independent:
//   S[k][v]_t = g_t*S[k][v]_{t-1} + k_t[k]*delta_t[v]
// grid: (DV/16 = 8 column groups, HV = 16 heads); block 256 = 16 cols x 16 subs
// each thread holds 8 state rows (sub*8 .. sub*8+7) of one column.
// ---------------------------------------------------------------------------
struct StepIn {
    float k[8];
    float q[8];
    float v, g, b;
};

__device__ __forceinline__ void load_step(StepIn& st, int t, int hk, int h, int sub, int v,
                                          const float* __restrict__ qc,
                                          const float* __restrict__ kc,
                                          const float* __restrict__ vc,
                                          const float* __restrict__ gb,
                                          const float* __restrict__ bb) {
    const float* kp = &kc[((size_t)t * HK_ + hk) * DK_ + sub * 8];
    const float* qp = &qc[((size_t)t * HK_ + hk) * DK_ + sub * 8];
    float4 k0 = *(const float4*)(kp);
    float4 k1 = *(const float4*)(kp + 4);
    float4 q0 = *(const float4*)(qp);
    float4 q1 = *(const float4*)(qp + 4);
    st.k[0] = k0.x; st.k[1] = k0.y; st.k[2] = k0.z; st.k[3] = k0.w;
    st.k[4] = k1.x; st.k[5] = k1.y; st.k[6] = k1.z; st.k[7] = k1.w;
    st.q[0] = q0.x; st.q[1] = q0.y; st.q[2] = q0.z; st.q[3] = q0.w;
    st.q[4] = q1.x; st.q[5] = q1.y; st.q[6] = q1.z; st.q[7] = q1.w;
    st.v = vc[((size_t)t * HV_ + h) * DV_ + v];
    st.g = gb[t * HV_ + h];
    st.b = bb[t * HV_ + h];
}

__device__ __forceinline__ void do_step(const StepIn& st, float Sreg[8], int t, int h, int v,
                                        int sub, float* __restrict__ core) {
    float dot = 0.f;
#pragma unroll
    for (int i = 0; i < 8; ++i) dot += st.k[i] * Sreg[i];
    dot += __shfl_xor(dot, 1);
    dot += __shfl_xor(dot, 2);
    dot += __shfl_xor(dot, 4);
    dot += __shfl_xor(dot, 8);
    float delta = (st.v - st.g * dot) * st.b;
    float o = 0.f;
#pragma unroll
    for (int i = 0; i < 8; ++i) {
        Sreg[i] = st.g * Sreg[i] + st.k[i] * delta;
        o += st.q[i] * Sreg[i];
    }
    o += __shfl_xor(o, 1);
    o += __shfl_xor(o, 2);
    o += __shfl_xor(o, 4);
    o += __shfl_xor(o, 8);
    if (sub == 0) core[((size_t)t * HV_ + h) * DV_ + v] = o;
}

__global__ __launch_bounds__(256) void scan_kernel(const float* __restrict__ qc,
                                                   const float* __restrict__ kc,
                                                   const float* __restrict__ vc,
                                                   const float* __restrict__ gb,
                                                   const float* __restrict__ bb,
                                                   float* __restrict__ core) {
    const int h   = blockIdx.y;            // head 0..15
    const int v0  = blockIdx.x * 16;       // column group
    const int tid = threadIdx.x;
    const int col = tid >> 4;              // 0..15
    const int sub = tid & 15;              // 0..15 (k-chunk)
    const int v   = v0 + col;
    const int hk  = h >> 1;

    float Sreg[8] = {0.f, 0.f, 0.f, 0.f, 0.f, 0.f, 0.f, 0.f};

    StepIn s0, s1, s2;
    load_step(s0, 0, hk, h, sub, v, qc, kc, vc, gb, bb);
    load_step(s1, 1, hk, h, sub, v, qc, kc, vc, gb, bb);
    load_step(s2, 2, hk, h, sub, v, qc, kc, vc, gb, bb);

    for (int t = 0; t < S_; t += 3) {
        do_step(s0, Sreg, t, h, v, sub, core);
        if (t + 3 < S_) load_step(s0, t + 3, hk, h, sub, v, qc, kc, vc, gb, bb);
        if (t + 1 < S_) {
            do_step(s1, Sreg, t + 1, h, v, sub, core);
            if (t + 4 < S_) load_step(s1, t + 4, hk, h, sub, v, qc, kc, vc, gb, bb);
        }
        if (t + 2 < S_) {
            do_step(s2, Sreg, t + 2, h, v, sub, core);
            if (t + 5 < S_) load_step(s2, t + 5, hk, h, sub, v, qc, kc, vc, gb, bb);
        }
    }
}

// ---------------------------------------------------------------------------
// RMS-norm over DV + gate with silu(z): out = core*rsqrt(mean(core^2)+eps)*w*silu(z)
// grid (S, HV), block 128.
// ---------------------------------------------------------------------------
__global__ __launch_bounds__(128) void normgate_kernel(const float* __restrict__ core,
                                                       const float* __restrict__ qkvz,
                                                       const float* __restrict__ nw,
                                                       float* __restrict__ outbuf) {
    const int s  = blockIdx.x;
    const int hv = blockIdx.y;
    const int d  = threadIdx.x;

    float x = core[((size_t)s * HV_ + hv) * DV_ + d];
    float ss = x * x;
#pragma unroll
    for (int m = 1; m < 64; m <<= 1) ss += __shfl_xor(ss, m);
    __shared__ float red[2];
    int wid = threadIdx.x >> 6;
    if ((threadIdx.x & 63) == 0) red[wid] = ss;
    __syncthreads();
    float var = (red[0] + red[1]) * (1.f / 128.f);
    float rs  = rsqrtf(var + EPS_);

    float z  = qkvz[(size_t)s * QKVZ_N + (hv >> 1) * 768 + 512 + (hv & 1) * 128 + d];
    float sz = z / (1.f + expf(-z));

    outbuf[(size_t)s * VAL_DIM_ + hv * DV_ + d] = x * rs * nw[d] * sz;
}

// ---------------------------------------------------------------------------
// launch
// ---------------------------------------------------------------------------
extern "C" void kernel_launch(void* const* d_in, const int* in_sizes, int n_in,
                              void* d_out, int out_size, void* d_ws, size_t ws_size,
                              hipStream_t stream) {
    const float* hidden  = (const float*)d_in[0];
    const float* W_qkvz  = (const float*)d_in[1];
    const float* W_ba    = (const float*)d_in[2];
    const float* conv_w  = (const float*)d_in[3];
    const float* dt_bias = (const float*)d_in[4];
    const float* A_log   = (const float*)d_in[5];
    const float* norm_w  = (const float*)d_in[6];
    const float* W_out   = (const float*)d_in[7];
    float* out = (float*)d_out;

    float* ws = (float*)d_ws;
    size_t off = 0;
    float* qkvz = ws + off; off += (size_t)S_ * QKVZ_N;   // 3145728
    float* ba   = ws + off; off += (size_t)S_ * 32;       // 16384
    float* qc   = ws + off; off += (size_t)S_ * KEY_DIM_; // 524288
    float* kc   = ws + off; off += (size_t)S_ * KEY_DIM_; // 524288
    float* vc   = ws + off; off += (size_t)S_ * VAL_DIM_; // 1048576
    float* gb   = ws + off; off += (size_t)S_ * HV_;      // 8192
    float* bb   = ws + off; off += (size_t)S_ * HV_;      // 8192
    float* core = ws + off; off += (size_t)S_ * VAL_DIM_; // 1048576
    float* nrm  = ws + off; off += (size_t)S_ * VAL_DIM_; // 1048576

    // 1. qkvz = hidden @ W_qkvz   (512 x 2048 x 6144)
    gemm_f32<<<dim3(QKVZ_N / TILE, S_ / TILE), 256, 0, stream>>>(
        hidden, W_qkvz, qkvz, S_, QKVZ_N, D_);

    // 2. ba = hidden @ W_ba
    ba_kernel<<<dim3((S_ * 32 + 255) / 256), 256, 0, stream>>>(hidden, W_ba, ba);

    // 3. conv + silu + l2norm
    conv_kernel<<<dim3(S_, 32), 128, 0, stream>>>(qkvz, conv_w, qc, kc, vc);

    // 4. gating
    gating_kernel<<<dim3((S_ * HV_ + 255) / 256), 256, 0, stream>>>(ba, A_log, dt_bias, gb, bb);

    // 5. gated delta-rule scan
    scan_kernel<<<dim3(DV_ / 16, HV_), 256, 0, stream>>>(qc, kc, vc, gb, bb, core);

    // 6. RMS norm + silu(z) gate
    normgate_kernel<<<dim3(S_, HV_), 128, 0, stream>>>(core, qkvz, norm_w, nrm);

    // 7. out = nrm @ W_out   (512 x 2048 x 2048)
    gemm_f32<<<dim3(D_ / TILE, S_ / TILE), 256, 0, stream>>>(
        nrm, W_out, out, S_, D_, VAL_DIM_);
}

// Round 2
// 721.956 us; speedup vs baseline: 1.2102x; 1.2102x over previous
//
#include <hip/hip_runtime.h>
#include <hip/hip_bf16.h>
#include <math.h>

// Problem constants
#define B_  1
#define S_  512
#define D_  2048
#define HK_ 8
#define HV_ 16
#define DK_ 128
#define DV_ 128
#define KC_ 4
#define R_  2
#define KEY_DIM_ 1024
#define VAL_DIM_ 2048
#define QKVZ_N  6144
#define EPS_ 1e-6f

typedef __attribute__((ext_vector_type(8))) short short8;
typedef __attribute__((ext_vector_type(4))) float f32x4;
typedef unsigned short ushort_t;
typedef unsigned int uint_t;

// ---------------------------------------------------------------------------
// bf16 split helpers (round-to-nearest-even)
// ---------------------------------------------------------------------------
__device__ __forceinline__ ushort_t f2bf(float x) {
    uint_t u = __float_as_uint(x);
    uint_t r = (u + 0x7FFFu + ((u >> 16) & 1u)) >> 16;
    return (ushort_t)r;
}
__device__ __forceinline__ float bf_hi_f(float x) {
    uint_t u = __float_as_uint(x);
    uint_t r = (u + 0x7FFFu + ((u >> 16) & 1u)) & 0xFFFF0000u;
    return __uint_as_float(r);
}

// ---------------------------------------------------------------------------
// convert fp32 -> bf16 hi/lo planes (same layout)
// ---------------------------------------------------------------------------
__global__ __launch_bounds__(256) void convert_pair(const float* __restrict__ X,
                                                    ushort_t* __restrict__ H,
                                                    ushort_t* __restrict__ L,
                                                    int n4) {  // n4 = elements/4
    int i = blockIdx.x * blockDim.x + threadIdx.x;
    if (i >= n4) return;
    float4 v = ((const float4*)X)[i];
    float h0 = bf_hi_f(v.x), h1 = bf_hi_f(v.y), h2 = bf_hi_f(v.z), h3 = bf_hi_f(v.w);
    ushort4 h, l;
    h.x = f2bf(v.x); h.y = f2bf(v.y); h.z = f2bf(v.z); h.w = f2bf(v.w);
    l.x = f2bf(v.x - h0); l.y = f2bf(v.y - h1); l.z = f2bf(v.z - h2); l.w = f2bf(v.w - h3);
    ((ushort4*)H)[i] = h;
    ((ushort4*)L)[i] = l;
}

// ---------------------------------------------------------------------------
// W[K][N] fp32 -> T_hi/T_lo[N][K] bf16 planes (transpose + split-convert)
// grid (N/64, K/64), block 256
// ---------------------------------------------------------------------------
__global__ __launch_bounds__(256) void transpose_convert(const float* __restrict__ W,
                                                         ushort_t* __restrict__ Th,
                                                         ushort_t* __restrict__ Tl,
                                                         int K, int N) {
    __shared__ float tile[64][65];
    const int kb = blockIdx.y * 64, nb = blockIdx.x * 64;
    const int t = threadIdx.x;
#pragma unroll
    for (int i = 0; i < 4; ++i) {
        int r = (t >> 4) + i * 16;
        int c4 = (t & 15) * 4;
        float4 v = *(const float4*)&W[(size_t)(kb + r) * N + nb + c4];
        tile[r][c4 + 0] = v.x; tile[r][c4 + 1] = v.y;
        tile[r][c4 + 2] = v.z; tile[r][c4 + 3] = v.w;
    }
    __syncthreads();
#pragma unroll
    for (int i = 0; i < 4; ++i) {
        int idx = t + 256 * i;
        int n = idx >> 4;
        int k4 = (idx & 15) * 4;
        float x0 = tile[k4 + 0][n], x1 = tile[k4 + 1][n];
        float x2 = tile[k4 + 2][n], x3 = tile[k4 + 3][n];
        ushort4 h, l;
        h.x = f2bf(x0); h.y = f2bf(x1); h.z = f2bf(x2); h.w = f2bf(x3);
        l.x = f2bf(x0 - bf_hi_f(x0)); l.y = f2bf(x1 - bf_hi_f(x1));
        l.z = f2bf(x2 - bf_hi_f(x2)); l.w = f2bf(x3 - bf_hi_f(x3));
        *(ushort4*)&Th[(size_t)(nb + n) * K + kb + k4] = h;
        *(ushort4*)&Tl[(size_t)(nb + n) * K + kb + k4] = l;
    }
}

// ---------------------------------------------------------------------------
// 3-pass split-bf16 MFMA GEMM: C[M][N] (fp32) = A[M][K] @ B^T (B given [N][K])
// A,B given as bf16 hi/lo planes. BK=32 (one 16x16x32 MFMA K-step).
// 256 threads = 4 waves arranged WR x WC; per-wave TM x TN 16x16 tiles.
// LDS XOR-swizzled at 16B-chunk granularity -> <=2-way bank conflicts.
// ---------------------------------------------------------------------------
__device__ __forceinline__ int swz(int m) { return (m ^ (m >> 2)) & 3; }

template<int BM, int BN, int WR, int WC>
__global__ __launch_bounds__(256) void gemm3p(const ushort_t* __restrict__ Ah,
                                              const ushort_t* __restrict__ Al,
                                              const ushort_t* __restrict__ Bh,
                                              const ushort_t* __restrict__ Bl,
                                              float* __restrict__ C,
                                              int M, int N, int K) {
    constexpr int TM = BM / (16 * WR);
    constexpr int TN = BN / (16 * WC);
    constexpr int IA = (BM * 4) / 256;   // 16B chunks per thread for A plane
    constexpr int IB = (BN * 4) / 256;

    __shared__ __align__(16) ushort_t sAh[BM * 32];
    __shared__ __align__(16) ushort_t sAl[BM * 32];
    __shared__ __align__(16) ushort_t sBh[BN * 32];
    __shared__ __align__(16) ushort_t sBl[BN * 32];

    const int t = threadIdx.x;
    const int w = t >> 6, lane = t & 63;
    const int wr = w / WC, wc = w % WC;
    const int lm = lane & 15;
    const int quad = lane >> 4;

    const int m0 = blockIdx.y * BM;
    const int n0 = blockIdx.x * BN;

    f32x4 acc[TM][TN] = {};

    for (int k0 = 0; k0 < K; k0 += 32) {
        uint4 rah[IA], ral[IA], rbh[IB], rbl[IB];
#pragma unroll
        for (int i = 0; i < IA; ++i) {
            int idx = t + 256 * i;
            int m = idx >> 2, c = idx & 3;
            size_t off = (size_t)(m0 + m) * K + k0 + c * 8;
            rah[i] = *(const uint4*)(Ah + off);
            ral[i] = *(const uint4*)(Al + off);
        }
#pragma unroll
        for (int i = 0; i < IB; ++i) {
            int idx = t + 256 * i;
            int n = idx >> 2, c = idx & 3;
            size_t off = (size_t)(n0 + n) * K + k0 + c * 8;
            rbh[i] = *(const uint4*)(Bh + off);
            rbl[i] = *(const uint4*)(Bl + off);
        }
        __syncthreads();
#pragma unroll
        for (int i = 0; i < IA; ++i) {
            int idx = t + 256 * i;
            int m = idx >> 2, c = idx & 3;
            int cs = c ^ swz(m);
            *(uint4*)&sAh[m * 32 + cs * 8] = rah[i];
            *(uint4*)&sAl[m * 32 + cs * 8] = ral[i];
        }
#pragma unroll
        for (int i = 0; i < IB; ++i) {
            int idx = t + 256 * i;
            int n = idx >> 2, c = idx & 3;
            int cs = c ^ swz(n);
            *(uint4*)&sBh[n * 32 + cs * 8] = rbh[i];
            *(uint4*)&sBl[n * 32 + cs * 8] = rbl[i];
        }
        __syncthreads();

        short8 bh[TN], bl[TN];
#pragma unroll
        for (int ni = 0; ni < TN; ++ni) {
            int n = wc * TN * 16 + ni * 16 + lm;
            int cs = quad ^ swz(n);
            bh[ni] = *(const short8*)&sBh[n * 32 + cs * 8];
            bl[ni] = *(const short8*)&sBl[n * 32 + cs * 8];
        }
#pragma unroll
        for (int mi = 0; mi < TM; ++mi) {
            int m = wr * TM * 16 + mi * 16 + lm;
            int cs = quad ^ swz(m);
            short8 ah = *(const short8*)&sAh[m * 32 + cs * 8];
            short8 al = *(const short8*)&sAl[m * 32 + cs * 8];
#pragma unroll
            for (int ni = 0; ni < TN; ++ni) {
                acc[mi][ni] = __builtin_amdgcn_mfma_f32_16x16x32_bf16(ah, bh[ni], acc[mi][ni], 0, 0, 0);
                acc[mi][ni] = __builtin_amdgcn_mfma_f32_16x16x32_bf16(ah, bl[ni], acc[mi][ni], 0, 0, 0);
                acc[mi][ni] = __builtin_amdgcn_mfma_f32_16x16x32_bf16(al, bh[ni], acc[mi][ni], 0, 0, 0);
            }
        }
    }
    // epilogue: D row = quad*4 + reg, col = lane&15  [m89-verified layout]
#pragma unroll
    for (int mi = 0; mi < TM; ++mi)
#pragma unroll
        for (int ni = 0; ni < TN; ++ni) {
            int row = m0 + wr * TM * 16 + mi * 16 + quad * 4;
            int col = n0 + wc * TN * 16 + ni * 16 + lm;
#pragma unroll
            for (int r = 0; r < 4; ++r)
                C[(size_t)(row + r) * N + col] = acc[mi][ni][r];
        }
}

// ---------------------------------------------------------------------------
// ba = hidden @ W_ba  (512x2048 @ 2048x32) — tiny, fp32
// ---------------------------------------------------------------------------
__global__ __launch_bounds__(256) void ba_kernel(const float* __restrict__ hid,
                                                 const float* __restrict__ Wba,
                                                 float* __restrict__ ba) {
    int id = blockIdx.x * blockDim.x + threadIdx.x;
    if (id >= S_ * 32) return;
    int s = id >> 5;
    int j = id & 31;
    float sum = 0.f;
    const float* hrow = hid + (size_t)s * D_;
#pragma unroll 8
    for (int k = 0; k < D_; ++k) sum += hrow[k] * Wba[(size_t)k * 32 + j];
    ba[id] = sum;
}

// ---------------------------------------------------------------------------
// causal depthwise conv (K=4) + silu + l2norm (q/k)
// ---------------------------------------------------------------------------
__global__ __launch_bounds__(128) void conv_kernel(const float* __restrict__ qkvz,
                                                   const float* __restrict__ conv_w,
                                                   float* __restrict__ qc,
                                                   float* __restrict__ kc,
                                                   float* __restrict__ vc) {
    const int s   = blockIdx.x;
    const int grp = blockIdx.y;
    const int d   = threadIdx.x;

    int col, c;
    if (grp < 8) {
        int hk = grp;
        col = hk * 768 + d;
        c   = hk * 128 + d;
    } else if (grp < 16) {
        int hk = grp - 8;
        col = hk * 768 + 128 + d;
        c   = 1024 + (hk * 128 + d);
    } else {
        int hv = grp - 16;
        col = (hv >> 1) * 768 + 256 + (hv & 1) * 128 + d;
        c   = 2048 + (hv * 128 + d);
    }

    const float w0 = conv_w[c * 4 + 0];
    const float w1 = conv_w[c * 4 + 1];
    const float w2 = conv_w[c * 4 + 2];
    const float w3 = conv_w[c * 4 + 3];

    float x = 0.f;
    if (s - 3 >= 0) x += qkvz[(size_t)(s - 3) * QKVZ_N + col] * w0;
    if (s - 2 >= 0) x += qkvz[(size_t)(s - 2) * QKVZ_N + col] * w1;
    if (s - 1 >= 0) x += qkvz[(size_t)(s - 1) * QKVZ_N + col] * w2;
    x += qkvz[(size_t)s * QKVZ_N + col] * w3;

    x = x / (1.f + expf(-x));

    if (grp < 16) {
        float ss = x * x;
#pragma unroll
        for (int m = 1; m < 64; m <<= 1) ss += __shfl_xor(ss, m);
        __shared__ float red[2];
        int wid = threadIdx.x >> 6;
        if ((threadIdx.x & 63) == 0) red[wid] = ss;
        __syncthreads();
        float tot = red[0] + red[1];
        float scale = rsqrtf(tot + EPS_);
        if (grp < 8) {
            x = x * scale * 0.08838834764831845f;
            qc[((size_t)s * HK_ + grp) * DK_ + d] = x;
        } else {
            x = x * scale;
            kc[((size_t)s * HK_ + (grp - 8)) * DK_ + d] = x;
        }
    } else {
        vc[((size_t)s * HV_ + (grp - 16)) * DV_ + d] = x;
    }
}

// ---------------------------------------------------------------------------
// gating
// ---------------------------------------------------------------------------
__global__ __launch_bounds__(256) void gating_kernel(const float* __restrict__ ba,
                                                     const float* __restrict__ A_log,
                                                     const float* __restrict__ dt_bias,
                                                     float* __restrict__ g,
                                                     float* __restrict__ beta) {
    int id = blockIdx.x * blockDim.x + threadIdx.x;
    if (id >= S_ * HV_) return;
    int s  = id >> 4;
    int hv = id & 15;
    int hk = hv >> 1;
    int r  = hv & 1;
    float b = ba[s * 32 + hk * 4 + r];
    float a = ba[s * 32 + hk * 4 + 2 + r];
    beta[id] = 1.f / (1.f + expf(-b));
    float x  = a + dt_bias[hv];
    float sp = (x > 20.f) ? x : log1pf(expf(x));
    g[id] = expf(-expf(A_log[hv]) * sp);
}

// ---------------------------------------------------------------------------
// gated delta-rule scan with DPP 16-lane reductions
// grid (DV/16, HV), block 256 = 16 cols x 16 subs; 8 state rows/thread
// ---------------------------------------------------------------------------
template<int CTRL>
__device__ __forceinline__ float dpp_xor(float x) {
    int v = __builtin_amdgcn_update_dpp(0, __float_as_int(x), CTRL, 0xF, 0xF, true);
    return __int_as_float(v);
}
__device__ __forceinline__ float red16(float x) {
    x += dpp_xor<0xB1>(x);   // quad_perm [1,0,3,2]  (xor 1)
    x += dpp_xor<0x4E>(x);   // quad_perm [2,3,0,1]  (xor 2)
    x += dpp_xor<0x141>(x);  // row_half_mirror      (xor 4)
    x += dpp_xor<0x140>(x);  // row_mirror           (xor 8)
    return x;
}
__device__ __forceinline__ float dot8(const float* a, const float* s) {
    float p0 = fmaf(a[4], s[4], a[0] * s[0]);
    float p1 = fmaf(a[5], s[5], a[1] * s[1]);
    float p2 = fmaf(a[6], s[6], a[2] * s[2]);
    float p3 = fmaf(a[7], s[7], a[3] * s[3]);
    return (p0 + p1) + (p2 + p3);
}

struct StepIn {
    float k[8];
    float q[8];
    float v, g, b;
};

__device__ __forceinline__ void load_step(StepIn& st, int t, int hk, int h, int sub, int v,
                                          const float* __restrict__ qc,
                                          const float* __restrict__ kc,
                                          const float* __restrict__ vc,
                                          const float* __restrict__ gb,
                                          const float* __restrict__ bb) {
    const float* kp = &kc[((size_t)t * HK_ + hk) * DK_ + sub * 8];
    const float* qp = &qc[((size_t)t * HK_ + hk) * DK_ + sub * 8];
    float4 k0 = *(const float4*)(kp);
    float4 k1 = *(const float4*)(kp + 4);
    float4 q0 = *(const float4*)(qp);
    float4 q1 = *(const float4*)(qp + 4);
    st.k[0] = k0.x; st.k[1] = k0.y; st.k[2] = k0.z; st.k[3] = k0.w;
    st.k[4] = k1.x; st.k[5] = k1.y; st.k[6] = k1.z; st.k[7] = k1.w;
    st.q[0] = q0.x; st.q[1] = q0.y; st.q[2] = q0.z; st.q[3] = q0.w;
    st.q[4] = q1.x; st.q[5] = q1.y; st.q[6] = q1.z; st.q[7] = q1.w;
    st.v = vc[((size_t)t * HV_ + h) * DV_ + v];
    st.g = gb[t * HV_ + h];
    st.b = bb[t * HV_ + h];
}

__device__ __forceinline__ void do_step(const StepIn& st, float Sreg[8], int t, int h, int v,
                                        int sub, float* __restrict__ core) {
    float dk = red16(dot8(st.k, Sreg));
    float delta = fmaf(-st.g, dk, st.v) * st.b;
#pragma unroll
    for (int i = 0; i < 8; ++i)
        Sreg[i] = fmaf(st.k[i], delta, st.g * Sreg[i]);
    float o = red16(dot8(st.q, Sreg));
    if (sub == 0) core[((size_t)t * HV_ + h) * DV_ + v] = o;
}

__global__ __launch_bounds__(256) void scan_kernel(const float* __restrict__ qc,
                                                   const float* __restrict__ kc,
                                                   const float* __restrict__ vc,
                                                   const float* __restrict__ gb,
                                                   const float* __restrict__ bb,
                                                   float* __restrict__ core) {
    const int h   = blockIdx.y;
    const int v0  = blockIdx.x * 16;
    const int tid = threadIdx.x;
    const int col = tid >> 4;
    const int sub = tid & 15;
    const int v   = v0 + col;
    const int hk  = h >> 1;

    float Sreg[8] = {};

    StepIn s0, s1, s2;
    load_step(s0, 0, hk, h, sub, v, qc, kc, vc, gb, bb);
    load_step(s1, 1, hk, h, sub, v, qc, kc, vc, gb, bb);
    load_step(s2, 2, hk, h, sub, v, qc, kc, vc, gb, bb);

    for (int t = 0; t < S_; t += 3) {
        do_step(s0, Sreg, t, h, v, sub, core);
        if (t + 3 < S_) load_step(s0, t + 3, hk, h, sub, v, qc, kc, vc, gb, bb);
        if (t + 1 < S_) {
            do_step(s1, Sreg, t + 1, h, v, sub, core);
            if (t + 4 < S_) load_step(s1, t + 4, hk, h, sub, v, qc, kc, vc, gb, bb);
        }
        if (t + 2 < S_) {
            do_step(s2, Sreg, t + 2, h, v, sub, core);
            if (t + 5 < S_) load_step(s2, t + 5, hk, h, sub, v, qc, kc, vc, gb, bb);
        }
    }
}

// ---------------------------------------------------------------------------
// RMS-norm + silu(z) gate; emits bf16 hi/lo planes (feeds gemm2 directly)
// ---------------------------------------------------------------------------
__global__ __launch_bounds__(128) void normgate_kernel(const float* __restrict__ core,
                                                       const float* __restrict__ qkvz,
                                                       const float* __restrict__ nw,
                                                       ushort_t* __restrict__ nh,
                                                       ushort_t* __restrict__ nl) {
    const int s  = blockIdx.x;
    const int hv = blockIdx.y;
    const int d  = threadIdx.x;

    float x = core[((size_t)s * HV_ + hv) * DV_ + d];
    float ss = x * x;
#pragma unroll
    for (int m = 1; m < 64; m <<= 1) ss += __shfl_xor(ss, m);
    __shared__ float red[2];
    int wid = threadIdx.x >> 6;
    if ((threadIdx.x & 63) == 0) red[wid] = ss;
    __syncthreads();
    float var = (red[0] + red[1]) * (1.f / 128.f);
    float rs  = rsqrtf(var + EPS_);

    float z  = qkvz[(size_t)s * QKVZ_N + (hv >> 1) * 768 + 512 + (hv & 1) * 128 + d];
    float sz = z / (1.f + expf(-z));

    float y = x * rs * nw[d] * sz;
    size_t o = (size_t)s * VAL_DIM_ + hv * DV_ + d;
    nh[o] = f2bf(y);
    nl[o] = f2bf(y - bf_hi_f(y));
}

// ---------------------------------------------------------------------------
// launch
// ---------------------------------------------------------------------------
extern "C" void kernel_launch(void* const* d_in, const int* in_sizes, int n_in,
                              void* d_out, int out_size, void* d_ws, size_t ws_size,
                              hipStream_t stream) {
    const float* hidden  = (const float*)d_in[0];
    const float* W_qkvz  = (const float*)d_in[1];
    const float* W_ba    = (const float*)d_in[2];
    const float* conv_w  = (const float*)d_in[3];
    const float* dt_bias = (const float*)d_in[4];
    const float* A_log   = (const float*)d_in[5];
    const float* norm_w  = (const float*)d_in[6];
    const float* W_out   = (const float*)d_in[7];
    float* out = (float*)d_out;

    char* w = (char*)d_ws;
    auto alloc = [&](size_t bytes) { char* p = w; w += (bytes + 255) & ~(size_t)255; return p; };

    float*    qkvz = (float*)alloc((size_t)S_ * QKVZ_N * 4);
    float*    ba   = (float*)alloc((size_t)S_ * 32 * 4);
    float*    qc   = (float*)alloc((size_t)S_ * KEY_DIM_ * 4);
    float*    kc   = (float*)alloc((size_t)S_ * KEY_DIM_ * 4);
    float*    vc   = (float*)alloc((size_t)S_ * VAL_DIM_ * 4);
    float*    gb   = (float*)alloc((size_t)S_ * HV_ * 4);
    float*    bb   = (float*)alloc((size_t)S_ * HV_ * 4);
    float*    core = (float*)alloc((size_t)S_ * VAL_DIM_ * 4);
    ushort_t* hidh = (ushort_t*)alloc((size_t)S_ * D_ * 2);
    ushort_t* hidl = (ushort_t*)alloc((size_t)S_ * D_ * 2);
    ushort_t* nrmh = (ushort_t*)alloc((size_t)S_ * VAL_DIM_ * 2);
    ushort_t* nrml = (ushort_t*)alloc((size_t)S_ * VAL_DIM_ * 2);
    ushort_t* Wqh  = (ushort_t*)alloc((size_t)D_ * QKVZ_N * 2);
    ushort_t* Wql  = (ushort_t*)alloc((size_t)D_ * QKVZ_N * 2);
    ushort_t* Woh  = (ushort_t*)alloc((size_t)VAL_DIM_ * D_ * 2);
    ushort_t* Wol  = (ushort_t*)alloc((size_t)VAL_DIM_ * D_ * 2);

    // 0a. hidden -> bf16 hi/lo planes
    convert_pair<<<dim3((S_ * D_ / 4 + 255) / 256), 256, 0, stream>>>(hidden, hidh, hidl, S_ * D_ / 4);
    // 0b. W_qkvz [2048][6144] -> [6144][2048] planes
    transpose_convert<<<dim3(QKVZ_N / 64, D_ / 64), 256, 0, stream>>>(W_qkvz, Wqh, Wql, D_, QKVZ_N);
    // 0c. W_out [2048][2048] -> [2048][2048] planes (transposed)
    transpose_convert<<<dim3(D_ / 64, VAL_DIM_ / 64), 256, 0, stream>>>(W_out, Woh, Wol, VAL_DIM_, D_);

    // 1. qkvz = hidden @ W_qkvz : 3-pass split-bf16 MFMA
    gemm3p<128, 128, 2, 2><<<dim3(QKVZ_N / 128, S_ / 128), 256, 0, stream>>>(
        hidh, hidl, Wqh, Wql, qkvz, S_, QKVZ_N, D_);

    // 2. ba
    ba_kernel<<<dim3((S_ * 32 + 255) / 256), 256, 0, stream>>>(hidden, W_ba, ba);

    // 3. conv + silu + l2norm
    conv_kernel<<<dim3(S_, 32), 128, 0, stream>>>(qkvz, conv_w, qc, kc, vc);

    // 4. gating
    gating_kernel<<<dim3((S_ * HV_ + 255) / 256), 256, 0, stream>>>(ba, A_log, dt_bias, gb, bb);

    // 5. scan (DPP)
    scan_kernel<<<dim3(DV_ / 16, HV_), 256, 0, stream>>>(qc, kc, vc, gb, bb, core);

    // 6. RMS norm + gate -> bf16 planes
    normgate_kernel<<<dim3(S_, HV_), 128, 0, stream>>>(core, qkvz, norm_w, nrmh, nrml);

    // 7. out = nrm @ W_out : 3-pass split-bf16 MFMA (64-row tiles -> 128 blocks)
    gemm3p<64, 128, 1, 4><<<dim3(D_ / 128, S_ / 64), 256, 0, stream>>>(
        nrmh, nrml, Woh, Wol, out, S_, D_, VAL_DIM_);
}

// Round 3
// 297.511 us; speedup vs baseline: 2.9368x; 2.4267x over previous
//
#include <hip/hip_runtime.h>
#include <hip/hip_bf16.h>
#include <math.h>

// Problem constants
#define S_  512
#define D_  2048
#define HK_ 8
#define HV_ 16
#define DK_ 128
#define DV_ 128
#define KEY_DIM_ 1024
#define VAL_DIM_ 2048
#define QKVZ_N  6144
#define EPS_ 1e-6f

typedef __attribute__((ext_vector_type(8))) short short8;
typedef __attribute__((ext_vector_type(4))) float f32x4;
typedef unsigned short ushort_t;
typedef unsigned int uint_t;

// ---------------------------------------------------------------------------
// helpers
// ---------------------------------------------------------------------------
__device__ __forceinline__ ushort_t f2bf(float x) {
    uint_t u = __float_as_uint(x);
    return (ushort_t)((u + 0x7FFFu + ((u >> 16) & 1u)) >> 16);
}

// async global->LDS, 16B per lane; dest = lds_base + lane*16 (wave-uniform base)
__device__ __forceinline__ void gl2lds16(const void* g, void* l) {
    __builtin_amdgcn_global_load_lds((const __attribute__((address_space(1))) uint_t*)g,
                                     (__attribute__((address_space(3))) uint_t*)l, 16, 0, 0);
}
// async global->LDS, 4B per lane; dest = lds_base + lane*4
__device__ __forceinline__ void gl2lds4(const void* g, void* l) {
    __builtin_amdgcn_global_load_lds((const __attribute__((address_space(1))) uint_t*)g,
                                     (__attribute__((address_space(3))) uint_t*)l, 4, 0, 0);
}

// ---------------------------------------------------------------------------
// fp32 -> bf16 (flat)
// ---------------------------------------------------------------------------
__global__ __launch_bounds__(256) void convert_bf16(const float* __restrict__ X,
                                                    ushort_t* __restrict__ H, int n4) {
    int i = blockIdx.x * blockDim.x + threadIdx.x;
    if (i >= n4) return;
    float4 v = ((const float4*)X)[i];
    ushort4 h;
    h.x = f2bf(v.x); h.y = f2bf(v.y); h.z = f2bf(v.z); h.w = f2bf(v.w);
    ((ushort4*)H)[i] = h;
}

// ---------------------------------------------------------------------------
// W[K][N] fp32 -> T[N][K] bf16 (transpose + convert); grid (N/64, K/64), 256 thr
// ---------------------------------------------------------------------------
__global__ __launch_bounds__(256) void transpose_convert(const float* __restrict__ W,
                                                         ushort_t* __restrict__ Th,
                                                         int K, int N) {
    __shared__ float tile[64][65];
    const int kb = blockIdx.y * 64, nb = blockIdx.x * 64;
    const int t = threadIdx.x;
#pragma unroll
    for (int i = 0; i < 4; ++i) {
        int r = (t >> 4) + i * 16;
        int c4 = (t & 15) * 4;
        float4 v = *(const float4*)&W[(size_t)(kb + r) * N + nb + c4];
        tile[r][c4 + 0] = v.x; tile[r][c4 + 1] = v.y;
        tile[r][c4 + 2] = v.z; tile[r][c4 + 3] = v.w;
    }
    __syncthreads();
#pragma unroll
    for (int i = 0; i < 4; ++i) {
        int idx = t + 256 * i;
        int n = idx >> 4;
        int k4 = (idx & 15) * 4;
        ushort4 h;
        h.x = f2bf(tile[k4 + 0][n]); h.y = f2bf(tile[k4 + 1][n]);
        h.z = f2bf(tile[k4 + 2][n]); h.w = f2bf(tile[k4 + 3][n]);
        *(ushort4*)&Th[(size_t)(nb + n) * K + kb + k4] = h;
    }
}

// ---------------------------------------------------------------------------
// bf16 MFMA GEMM, m97 structure: C[M][N] fp32 = A[M][K] @ B^T (B given [N][K]).
// BK=64 (2 MFMA k-steps), double-buffered LDS, global_load_lds(16B) staging,
// one barrier per K-iter; prefetch next tile before computing current.
// ---------------------------------------------------------------------------
template<int BM, int BN, int WR, int WC>
__global__ __launch_bounds__(256) void gemm_bf16(const ushort_t* __restrict__ A,
                                                 const ushort_t* __restrict__ B,
                                                 float* __restrict__ C,
                                                 int M, int N, int K) {
    constexpr int TM = BM / (16 * WR);
    constexpr int TN = BN / (16 * WC);
    constexpr int AI = (BM / 16) * 2;   // 1KB staging insts per k64 iter (A)
    constexpr int BI = (BN / 16) * 2;

    __shared__ __align__(16) ushort_t sA[2][2][BM][32];
    __shared__ __align__(16) ushort_t sB[2][2][BN][32];

    const int t = threadIdx.x;
    const int w = t >> 6, lane = t & 63;
    const int wr = w / WC, wc = w % WC;
    const int lm = lane & 15, quad = lane >> 4;
    const int m0 = blockIdx.y * BM, n0 = blockIdx.x * BN;
    const int lrow = lane >> 2;          // 0..15
    const int lch  = (lane & 3) * 8;     // short offset of 16B chunk

    auto stage = [&](int buf, int k0) {
#pragma unroll
        for (int j = w; j < AI; j += 4) {
            int ks = j & 1, r0 = (j >> 1) * 16;
            gl2lds16(&A[(size_t)(m0 + r0 + lrow) * K + k0 + ks * 32 + lch],
                     &sA[buf][ks][r0][0]);
        }
#pragma unroll
        for (int j = w; j < BI; j += 4) {
            int ks = j & 1, r0 = (j >> 1) * 16;
            gl2lds16(&B[(size_t)(n0 + r0 + lrow) * K + k0 + ks * 32 + lch],
                     &sB[buf][ks][r0][0]);
        }
    };

    f32x4 acc[TM][TN] = {};
    stage(0, 0);
    __syncthreads();

    const int NK = K / 64;
    for (int it = 0; it < NK; ++it) {
        int buf = it & 1;
        if (it + 1 < NK) stage(buf ^ 1, (it + 1) * 64);
#pragma unroll
        for (int ks = 0; ks < 2; ++ks) {
            short8 bf[TN];
#pragma unroll
            for (int ni = 0; ni < TN; ++ni)
                bf[ni] = *(const short8*)&sB[buf][ks][wc * (TN * 16) + ni * 16 + lm][quad * 8];
#pragma unroll
            for (int mi = 0; mi < TM; ++mi) {
                short8 af = *(const short8*)&sA[buf][ks][wr * (TM * 16) + mi * 16 + lm][quad * 8];
#pragma unroll
                for (int ni = 0; ni < TN; ++ni)
                    acc[mi][ni] = __builtin_amdgcn_mfma_f32_16x16x32_bf16(af, bf[ni], acc[mi][ni], 0, 0, 0);
            }
        }
        __syncthreads();
    }

    // epilogue: C row = quad*4 + reg, col = lane&15 (m89-verified)
#pragma unroll
    for (int mi = 0; mi < TM; ++mi)
#pragma unroll
        for (int ni = 0; ni < TN; ++ni) {
            int row = m0 + wr * TM * 16 + mi * 16 + quad * 4;
            int col = n0 + wc * TN * 16 + ni * 16 + lm;
#pragma unroll
            for (int r = 0; r < 4; ++r)
                C[(size_t)(row + r) * N + col] = acc[mi][ni][r];
        }
}

// ---------------------------------------------------------------------------
// ba = hidden @ W_ba  (512x2048 @ 2048x32). One block per row s.
// thread (kg = t>>5, j = t&31): partial over 256 k; LDS reduce over kg.
// ---------------------------------------------------------------------------
__global__ __launch_bounds__(256) void ba_kernel(const float* __restrict__ hid,
                                                 const float* __restrict__ Wba,
                                                 float* __restrict__ ba) {
    const int s = blockIdx.x;
    const int j = threadIdx.x & 31;
    const int kg = threadIdx.x >> 5;
    const float* h = hid + (size_t)s * D_;
    float sum = 0.f;
    const int k0 = kg * 256;
#pragma unroll 8
    for (int k = k0; k < k0 + 256; ++k)
        sum = fmaf(h[k], Wba[(size_t)k * 32 + j], sum);
    __shared__ float red[8][32];
    red[kg][j] = sum;
    __syncthreads();
    if (threadIdx.x < 32) {
        float tot = 0.f;
#pragma unroll
        for (int r = 0; r < 8; ++r) tot += red[r][j];
        ba[s * 32 + j] = tot;
    }
}

// ---------------------------------------------------------------------------
// causal depthwise conv (K=4) + silu + l2norm (q/k). grid (S,32), block 128.
// ---------------------------------------------------------------------------
__global__ __launch_bounds__(128) void conv_kernel(const float* __restrict__ qkvz,
                                                   const float* __restrict__ conv_w,
                                                   float* __restrict__ qc,
                                                   float* __restrict__ kc,
                                                   float* __restrict__ vc) {
    const int s   = blockIdx.x;
    const int grp = blockIdx.y;
    const int d   = threadIdx.x;

    int col, c;
    if (grp < 8) {
        int hk = grp;
        col = hk * 768 + d;
        c   = hk * 128 + d;
    } else if (grp < 16) {
        int hk = grp - 8;
        col = hk * 768 + 128 + d;
        c   = 1024 + (hk * 128 + d);
    } else {
        int hv = grp - 16;
        col = (hv >> 1) * 768 + 256 + (hv & 1) * 128 + d;
        c   = 2048 + (hv * 128 + d);
    }

    const float w0 = conv_w[c * 4 + 0];
    const float w1 = conv_w[c * 4 + 1];
    const float w2 = conv_w[c * 4 + 2];
    const float w3 = conv_w[c * 4 + 3];

    float x = 0.f;
    if (s - 3 >= 0) x += qkvz[(size_t)(s - 3) * QKVZ_N + col] * w0;
    if (s - 2 >= 0) x += qkvz[(size_t)(s - 2) * QKVZ_N + col] * w1;
    if (s - 1 >= 0) x += qkvz[(size_t)(s - 1) * QKVZ_N + col] * w2;
    x += qkvz[(size_t)s * QKVZ_N + col] * w3;

    x = x / (1.f + expf(-x));

    if (grp < 16) {
        float ss = x * x;
#pragma unroll
        for (int m = 1; m < 64; m <<= 1) ss += __shfl_xor(ss, m);
        __shared__ float red[2];
        int wid = threadIdx.x >> 6;
        if ((threadIdx.x & 63) == 0) red[wid] = ss;
        __syncthreads();
        float tot = red[0] + red[1];
        float scale = rsqrtf(tot + EPS_);
        if (grp < 8) {
            x = x * scale * 0.08838834764831845f;   // * DK^-0.5
            qc[((size_t)s * HK_ + grp) * DK_ + d] = x;
        } else {
            x = x * scale;
            kc[((size_t)s * HK_ + (grp - 8)) * DK_ + d] = x;
        }
    } else {
        vc[((size_t)s * HV_ + (grp - 16)) * DV_ + d] = x;
    }
}

// ---------------------------------------------------------------------------
// gating
// ---------------------------------------------------------------------------
__global__ __launch_bounds__(256) void gating_kernel(const float* __restrict__ ba,
                                                     const float* __restrict__ A_log,
                                                     const float* __restrict__ dt_bias,
                                                     float* __restrict__ g,
                                                     float* __restrict__ beta) {
    int id = blockIdx.x * blockDim.x + threadIdx.x;
    if (id >= S_ * HV_) return;
    int s  = id >> 4;
    int hv = id & 15;
    int hk = hv >> 1;
    int r  = hv & 1;
    float b = ba[s * 32 + hk * 4 + r];
    float a = ba[s * 32 + hk * 4 + 2 + r];
    beta[id] = 1.f / (1.f + expf(-b));
    float x  = a + dt_bias[hv];
    float sp = (x > 20.f) ? x : log1pf(expf(x));
    g[id] = expf(-expf(A_log[hv]) * sp);
}

// ---------------------------------------------------------------------------
// gated delta-rule scan, LDS bulk-staged (32-step chunks, double-buffered).
// grid (DV/16, HV); block 256 = 16 cols x 16 subs; 8 state rows per thread.
// ---------------------------------------------------------------------------
template<int CTRL>
__device__ __forceinline__ float dpp_xor(float x) {
    int v = __builtin_amdgcn_update_dpp(0, __float_as_int(x), CTRL, 0xF, 0xF, true);
    return __int_as_float(v);
}
__device__ __forceinline__ float red16(float x) {
    x += dpp_xor<0xB1>(x);   // xor 1
    x += dpp_xor<0x4E>(x);   // xor 2
    x += dpp_xor<0x141>(x);  // xor 4 (row_half_mirror)
    x += dpp_xor<0x140>(x);  // xor 8 (row_mirror)
    return x;
}

__global__ __launch_bounds__(256) void scan_kernel(const float* __restrict__ qc,
                                                   const float* __restrict__ kc,
                                                   const float* __restrict__ vc,
                                                   const float* __restrict__ gb,
                                                   const float* __restrict__ bb,
                                                   float* __restrict__ core) {
    const int h = blockIdx.y, v0 = blockIdx.x * 16;
    const int t = threadIdx.x;
    const int col = t >> 4, sub = t & 15;
    const int lane = t & 63, w = t >> 6;
    const int v = v0 + col, hk = h >> 1;

    __shared__ __align__(16) float skq[2][32][256];  // [step][ k(128) | q(128) ]
    __shared__ __align__(16) float sv[2][32][16];
    __shared__ __align__(16) float sgb[2][64];       // g at [0..31], b at [32..63]

    auto stage = [&](int buf, int c) {
        int t0 = c * 32;
#pragma unroll
        for (int j = 0; j < 8; ++j) {                // 1 KB per step: k | q
            int st = w * 8 + j;
            int tt = t0 + st;
            const float* src = (lane < 32)
                ? &kc[((size_t)tt * HK_ + hk) * DK_ + lane * 4]
                : &qc[((size_t)tt * HK_ + hk) * DK_ + (lane - 32) * 4];
            gl2lds16(src, &skq[buf][st][0]);
        }
#pragma unroll
        for (int i = 0; i < 2; ++i) {                // v: 4 steps x 16 cols per inst
            int blk = w * 2 + i;
            int tt = t0 + blk * 4 + (lane >> 4);
            gl2lds4(&vc[((size_t)tt * HV_ + h) * DV_ + v0 + (lane & 15)],
                    &sv[buf][blk * 4][0]);
        }
        if (w == 0) {                                // g,b: one inst
            int tt = t0 + (lane & 31);
            const float* src = (lane < 32) ? &gb[(size_t)tt * HV_ + h]
                                           : &bb[(size_t)tt * HV_ + h];
            gl2lds4(src, &sgb[buf][0]);
        }
    };

    float S[8] = {};
    stage(0, 0);
    __syncthreads();

    for (int c = 0; c < 16; ++c) {
        const int buf = c & 1;
        if (c + 1 < 16) stage(buf ^ 1, c + 1);

        // depth-3 register pipeline over the 32 staged steps
        float4 kA[3][2], qA[3][2];
        float vr[3], gr[3], br[3];
        auto rd = [&](int slot, int j) {
            kA[slot][0] = *(const float4*)&skq[buf][j][sub * 8];
            kA[slot][1] = *(const float4*)&skq[buf][j][sub * 8 + 4];
            qA[slot][0] = *(const float4*)&skq[buf][j][128 + sub * 8];
            qA[slot][1] = *(const float4*)&skq[buf][j][128 + sub * 8 + 4];
            vr[slot] = sv[buf][j][col];
            gr[slot] = sgb[buf][j];
            br[slot] = sgb[buf][32 + j];
        };
        rd(0, 0); rd(1, 1);
#pragma unroll
        for (int j = 0; j < 32; ++j) {
            const int sl = j % 3;
            if (j + 2 < 32) rd((j + 2) % 3, j + 2);
            const float gg = gr[sl];
            // dot(k, S) over this thread's 8 rows
            float d0 = fmaf(kA[sl][0].x, S[0], kA[sl][1].x * S[4]);
            float d1 = fmaf(kA[sl][0].y, S[1], kA[sl][1].y * S[5]);
            float d2 = fmaf(kA[sl][0].z, S[2], kA[sl][1].z * S[6]);
            float d3 = fmaf(kA[sl][0].w, S[3], kA[sl][1].w * S[7]);
            float dk = red16((d0 + d1) + (d2 + d3));
            float delta = fmaf(-gg, dk, vr[sl]) * br[sl];
            S[0] = fmaf(kA[sl][0].x, delta, gg * S[0]);
            S[1] = fmaf(kA[sl][0].y, delta, gg * S[1]);
            S[2] = fmaf(kA[sl][0].z, delta, gg * S[2]);
            S[3] = fmaf(kA[sl][0].w, delta, gg * S[3]);
            S[4] = fmaf(kA[sl][1].x, delta, gg * S[4]);
            S[5] = fmaf(kA[sl][1].y, delta, gg * S[5]);
            S[6] = fmaf(kA[sl][1].z, delta, gg * S[6]);
            S[7] = fmaf(kA[sl][1].w, delta, gg * S[7]);
            float o0 = fmaf(qA[sl][0].x, S[0], qA[sl][1].x * S[4]);
            float o1 = fmaf(qA[sl][0].y, S[1], qA[sl][1].y * S[5]);
            float o2 = fmaf(qA[sl][0].z, S[2], qA[sl][1].z * S[6]);
            float o3 = fmaf(qA[sl][0].w, S[3], qA[sl][1].w * S[7]);
            float o = red16((o0 + o1) + (o2 + o3));
            if (sub == 0)
                core[((size_t)(c * 32 + j) * HV_ + h) * DV_ + v] = o;
        }
        __syncthreads();
    }
}

// ---------------------------------------------------------------------------
// RMS-norm + silu(z) gate -> bf16 (feeds gemm2 as A)
// ---------------------------------------------------------------------------
__global__ __launch_bounds__(128) void normgate_kernel(const float* __restrict__ core,
                                                       const float* __restrict__ qkvz,
                                                       const float* __restrict__ nw,
                                                       ushort_t* __restrict__ nh) {
    const int s  = blockIdx.x;
    const int hv = blockIdx.y;
    const int d  = threadIdx.x;

    float x = core[((size_t)s * HV_ + hv) * DV_ + d];
    float ss = x * x;
#pragma unroll
    for (int m = 1; m < 64; m <<= 1) ss += __shfl_xor(ss, m);
    __shared__ float red[2];
    int wid = threadIdx.x >> 6;
    if ((threadIdx.x & 63) == 0) red[wid] = ss;
    __syncthreads();
    float var = (red[0] + red[1]) * (1.f / 128.f);
    float rs  = rsqrtf(var + EPS_);

    float z  = qkvz[(size_t)s * QKVZ_N + (hv >> 1) * 768 + 512 + (hv & 1) * 128 + d];
    float sz = z / (1.f + expf(-z));

    float y = x * rs * nw[d] * sz;
    nh[(size_t)s * VAL_DIM_ + hv * DV_ + d] = f2bf(y);
}

// ---------------------------------------------------------------------------
// launch
// ---------------------------------------------------------------------------
extern "C" void kernel_launch(void* const* d_in, const int* in_sizes, int n_in,
                              void* d_out, int out_size, void* d_ws, size_t ws_size,
                              hipStream_t stream) {
    const float* hidden  = (const float*)d_in[0];
    const float* W_qkvz  = (const float*)d_in[1];
    const float* W_ba    = (const float*)d_in[2];
    const float* conv_w  = (const float*)d_in[3];
    const float* dt_bias = (const float*)d_in[4];
    const float* A_log   = (const float*)d_in[5];
    const float* norm_w  = (const float*)d_in[6];
    const float* W_out   = (const float*)d_in[7];
    float* out = (float*)d_out;

    char* w = (char*)d_ws;
    auto alloc = [&](size_t bytes) { char* p = w; w += (bytes + 255) & ~(size_t)255; return p; };

    float*    qkvz = (float*)alloc((size_t)S_ * QKVZ_N * 4);
    float*    ba   = (float*)alloc((size_t)S_ * 32 * 4);
    float*    qc   = (float*)alloc((size_t)S_ * KEY_DIM_ * 4);
    float*    kc   = (float*)alloc((size_t)S_ * KEY_DIM_ * 4);
    float*    vc   = (float*)alloc((size_t)S_ * VAL_DIM_ * 4);
    float*    gbuf = (float*)alloc((size_t)S_ * HV_ * 4);
    float*    bbuf = (float*)alloc((size_t)S_ * HV_ * 4);
    float*    core = (float*)alloc((size_t)S_ * VAL_DIM_ * 4);
    ushort_t* hidh = (ushort_t*)alloc((size_t)S_ * D_ * 2);
    ushort_t* nrmh = (ushort_t*)alloc((size_t)S_ * VAL_DIM_ * 2);
    ushort_t* Wqh  = (ushort_t*)alloc((size_t)D_ * QKVZ_N * 2);
    ushort_t* Woh  = (ushort_t*)alloc((size_t)VAL_DIM_ * D_ * 2);

    // 0a. hidden -> bf16
    convert_bf16<<<dim3((S_ * D_ / 4 + 255) / 256), 256, 0, stream>>>(hidden, hidh, S_ * D_ / 4);
    // 0b. W_qkvz [2048][6144] -> [6144][2048] bf16
    transpose_convert<<<dim3(QKVZ_N / 64, D_ / 64), 256, 0, stream>>>(W_qkvz, Wqh, D_, QKVZ_N);
    // 0c. W_out [2048][2048] -> [2048][2048] bf16 (transposed)
    transpose_convert<<<dim3(D_ / 64, VAL_DIM_ / 64), 256, 0, stream>>>(W_out, Woh, VAL_DIM_, D_);

    // 1. qkvz = hidden @ W_qkvz  (128x128 tiles, 48x4 = 192 blocks)
    gemm_bf16<128, 128, 2, 2><<<dim3(QKVZ_N / 128, S_ / 128), 256, 0, stream>>>(
        hidh, Wqh, qkvz, S_, QKVZ_N, D_);

    // 2. ba
    ba_kernel<<<dim3(S_), 256, 0, stream>>>(hidden, W_ba, ba);

    // 3. conv + silu + l2norm
    conv_kernel<<<dim3(S_, 32), 128, 0, stream>>>(qkvz, conv_w, qc, kc, vc);

    // 4. gating
    gating_kernel<<<dim3((S_ * HV_ + 255) / 256), 256, 0, stream>>>(ba, A_log, dt_bias, gbuf, bbuf);

    // 5. scan (LDS bulk-staged, DPP reductions)
    scan_kernel<<<dim3(DV_ / 16, HV_), 256, 0, stream>>>(qc, kc, vc, gbuf, bbuf, core);

    // 6. RMS norm + gate -> bf16
    normgate_kernel<<<dim3(S_, HV_), 128, 0, stream>>>(core, qkvz, norm_w, nrmh);

    // 7. out = nrm @ W_out  (64x64 tiles, 32x8 = 256 blocks)
    gemm_bf16<64, 64, 2, 2><<<dim3(D_ / 64, S_ / 64), 256, 0, stream>>>(
        nrmh, Woh, out, S_, D_, VAL_DIM_);
}

// Round 4
// 292.196 us; speedup vs baseline: 2.9902x; 1.0182x over previous
//
#include <hip/hip_runtime.h>
#include <hip/hip_bf16.h>
#include <math.h>

// Problem constants
#define S_  512
#define D_  2048
#define HK_ 8
#define HV_ 16
#define DK_ 128
#define DV_ 128
#define KEY_DIM_ 1024
#define VAL_DIM_ 2048
#define QKVZ_N  6144
#define EPS_ 1e-6f

typedef __attribute__((ext_vector_type(8))) short short8;
typedef __attribute__((ext_vector_type(4))) float f32x4;
typedef unsigned short ushort_t;
typedef unsigned int uint_t;

// ---------------------------------------------------------------------------
// helpers
// ---------------------------------------------------------------------------
__device__ __forceinline__ ushort_t f2bf(float x) {
    uint_t u = __float_as_uint(x);
    return (ushort_t)((u + 0x7FFFu + ((u >> 16) & 1u)) >> 16);
}

// async global->LDS, 16B per lane; dest = lds_base + lane*16 (wave-uniform base)
__device__ __forceinline__ void gl2lds16(const void* g, void* l) {
    __builtin_amdgcn_global_load_lds((const __attribute__((address_space(1))) uint_t*)g,
                                     (__attribute__((address_space(3))) uint_t*)l, 16, 0, 0);
}
// async global->LDS, 4B per lane; dest = lds_base + lane*4
__device__ __forceinline__ void gl2lds4(const void* g, void* l) {
    __builtin_amdgcn_global_load_lds((const __attribute__((address_space(1))) uint_t*)g,
                                     (__attribute__((address_space(3))) uint_t*)l, 4, 0, 0);
}

// ---------------------------------------------------------------------------
// fp32 -> bf16 (flat)
// ---------------------------------------------------------------------------
__global__ __launch_bounds__(256) void convert_bf16(const float* __restrict__ X,
                                                    ushort_t* __restrict__ H, int n4) {
    int i = blockIdx.x * blockDim.x + threadIdx.x;
    if (i >= n4) return;
    float4 v = ((const float4*)X)[i];
    ushort4 h;
    h.x = f2bf(v.x); h.y = f2bf(v.y); h.z = f2bf(v.z); h.w = f2bf(v.w);
    ((ushort4*)H)[i] = h;
}

// ---------------------------------------------------------------------------
// W[K][N] fp32 -> T[N][K] bf16 (transpose + convert); grid (N/64, K/64), 256 thr
// ---------------------------------------------------------------------------
__global__ __launch_bounds__(256) void transpose_convert(const float* __restrict__ W,
                                                         ushort_t* __restrict__ Th,
                                                         int K, int N) {
    __shared__ float tile[64][65];
    const int kb = blockIdx.y * 64, nb = blockIdx.x * 64;
    const int t = threadIdx.x;
#pragma unroll
    for (int i = 0; i < 4; ++i) {
        int r = (t >> 4) + i * 16;
        int c4 = (t & 15) * 4;
        float4 v = *(const float4*)&W[(size_t)(kb + r) * N + nb + c4];
        tile[r][c4 + 0] = v.x; tile[r][c4 + 1] = v.y;
        tile[r][c4 + 2] = v.z; tile[r][c4 + 3] = v.w;
    }
    __syncthreads();
#pragma unroll
    for (int i = 0; i < 4; ++i) {
        int idx = t + 256 * i;
        int n = idx >> 4;
        int k4 = (idx & 15) * 4;
        ushort4 h;
        h.x = f2bf(tile[k4 + 0][n]); h.y = f2bf(tile[k4 + 1][n]);
        h.z = f2bf(tile[k4 + 2][n]); h.w = f2bf(tile[k4 + 3][n]);
        *(ushort4*)&Th[(size_t)(nb + n) * K + kb + k4] = h;
    }
}

// ---------------------------------------------------------------------------
// bf16 MFMA GEMM, m97 structure: C[M][N] fp32 = A[M][K] @ B^T (B given [N][K]).
// BK=64, double-buffered LDS, global_load_lds(16B) staging, prefetch-1.
// ---------------------------------------------------------------------------
template<int BM, int BN, int WR, int WC>
__global__ __launch_bounds__(256) void gemm_bf16(const ushort_t* __restrict__ A,
                                                 const ushort_t* __restrict__ B,
                                                 float* __restrict__ C,
                                                 int M, int N, int K) {
    constexpr int TM = BM / (16 * WR);
    constexpr int TN = BN / (16 * WC);
    constexpr int AI = (BM / 16) * 2;
    constexpr int BI = (BN / 16) * 2;

    __shared__ __align__(16) ushort_t sA[2][2][BM][32];
    __shared__ __align__(16) ushort_t sB[2][2][BN][32];

    const int t = threadIdx.x;
    const int w = t >> 6, lane = t & 63;
    const int wr = w / WC, wc = w % WC;
    const int lm = lane & 15, quad = lane >> 4;
    const int m0 = blockIdx.y * BM, n0 = blockIdx.x * BN;
    const int lrow = lane >> 2;
    const int lch  = (lane & 3) * 8;

    auto stage = [&](int buf, int k0) {
#pragma unroll
        for (int j = w; j < AI; j += 4) {
            int ks = j & 1, r0 = (j >> 1) * 16;
            gl2lds16(&A[(size_t)(m0 + r0 + lrow) * K + k0 + ks * 32 + lch],
                     &sA[buf][ks][r0][0]);
        }
#pragma unroll
        for (int j = w; j < BI; j += 4) {
            int ks = j & 1, r0 = (j >> 1) * 16;
            gl2lds16(&B[(size_t)(n0 + r0 + lrow) * K + k0 + ks * 32 + lch],
                     &sB[buf][ks][r0][0]);
        }
    };

    f32x4 acc[TM][TN] = {};
    stage(0, 0);
    __syncthreads();

    const int NK = K / 64;
    for (int it = 0; it < NK; ++it) {
        int buf = it & 1;
        if (it + 1 < NK) stage(buf ^ 1, (it + 1) * 64);
#pragma unroll
        for (int ks = 0; ks < 2; ++ks) {
            short8 bf[TN];
#pragma unroll
            for (int ni = 0; ni < TN; ++ni)
                bf[ni] = *(const short8*)&sB[buf][ks][wc * (TN * 16) + ni * 16 + lm][quad * 8];
#pragma unroll
            for (int mi = 0; mi < TM; ++mi) {
                short8 af = *(const short8*)&sA[buf][ks][wr * (TM * 16) + mi * 16 + lm][quad * 8];
#pragma unroll
                for (int ni = 0; ni < TN; ++ni)
                    acc[mi][ni] = __builtin_amdgcn_mfma_f32_16x16x32_bf16(af, bf[ni], acc[mi][ni], 0, 0, 0);
            }
        }
        __syncthreads();
    }

#pragma unroll
    for (int mi = 0; mi < TM; ++mi)
#pragma unroll
        for (int ni = 0; ni < TN; ++ni) {
            int row = m0 + wr * TM * 16 + mi * 16 + quad * 4;
            int col = n0 + wc * TN * 16 + ni * 16 + lm;
#pragma unroll
            for (int r = 0; r < 4; ++r)
                C[(size_t)(row + r) * N + col] = acc[mi][ni][r];
        }
}

// ---------------------------------------------------------------------------
// ba = hidden @ W_ba  (512x2048 @ 2048x32). One block per row s.
// ---------------------------------------------------------------------------
__global__ __launch_bounds__(256) void ba_kernel(const float* __restrict__ hid,
                                                 const float* __restrict__ Wba,
                                                 float* __restrict__ ba) {
    const int s = blockIdx.x;
    const int j = threadIdx.x & 31;
    const int kg = threadIdx.x >> 5;
    const float* h = hid + (size_t)s * D_;
    float sum = 0.f;
    const int k0 = kg * 256;
#pragma unroll 8
    for (int k = k0; k < k0 + 256; ++k)
        sum = fmaf(h[k], Wba[(size_t)k * 32 + j], sum);
    __shared__ float red[8][32];
    red[kg][j] = sum;
    __syncthreads();
    if (threadIdx.x < 32) {
        float tot = 0.f;
#pragma unroll
        for (int r = 0; r < 8; ++r) tot += red[r][j];
        ba[s * 32 + j] = tot;
    }
}

// ---------------------------------------------------------------------------
// causal depthwise conv (K=4) + silu + l2norm (q/k). grid (S,32), block 128.
// ---------------------------------------------------------------------------
__global__ __launch_bounds__(128) void conv_kernel(const float* __restrict__ qkvz,
                                                   const float* __restrict__ conv_w,
                                                   float* __restrict__ qc,
                                                   float* __restrict__ kc,
                                                   float* __restrict__ vc) {
    const int s   = blockIdx.x;
    const int grp = blockIdx.y;
    const int d   = threadIdx.x;

    int col, c;
    if (grp < 8) {
        int hk = grp;
        col = hk * 768 + d;
        c   = hk * 128 + d;
    } else if (grp < 16) {
        int hk = grp - 8;
        col = hk * 768 + 128 + d;
        c   = 1024 + (hk * 128 + d);
    } else {
        int hv = grp - 16;
        col = (hv >> 1) * 768 + 256 + (hv & 1) * 128 + d;
        c   = 2048 + (hv * 128 + d);
    }

    const float w0 = conv_w[c * 4 + 0];
    const float w1 = conv_w[c * 4 + 1];
    const float w2 = conv_w[c * 4 + 2];
    const float w3 = conv_w[c * 4 + 3];

    float x = 0.f;
    if (s - 3 >= 0) x += qkvz[(size_t)(s - 3) * QKVZ_N + col] * w0;
    if (s - 2 >= 0) x += qkvz[(size_t)(s - 2) * QKVZ_N + col] * w1;
    if (s - 1 >= 0) x += qkvz[(size_t)(s - 1) * QKVZ_N + col] * w2;
    x += qkvz[(size_t)s * QKVZ_N + col] * w3;

    x = x / (1.f + expf(-x));

    if (grp < 16) {
        float ss = x * x;
#pragma unroll
        for (int m = 1; m < 64; m <<= 1) ss += __shfl_xor(ss, m);
        __shared__ float red[2];
        int wid = threadIdx.x >> 6;
        if ((threadIdx.x & 63) == 0) red[wid] = ss;
        __syncthreads();
        float tot = red[0] + red[1];
        float scale = rsqrtf(tot + EPS_);
        if (grp < 8) {
            x = x * scale * 0.08838834764831845f;   // * DK^-0.5
            qc[((size_t)s * HK_ + grp) * DK_ + d] = x;
        } else {
            x = x * scale;
            kc[((size_t)s * HK_ + (grp - 8)) * DK_ + d] = x;
        }
    } else {
        vc[((size_t)s * HV_ + (grp - 16)) * DV_ + d] = x;
    }
}

// ---------------------------------------------------------------------------
// gating
// ---------------------------------------------------------------------------
__global__ __launch_bounds__(256) void gating_kernel(const float* __restrict__ ba,
                                                     const float* __restrict__ A_log,
                                                     const float* __restrict__ dt_bias,
                                                     float* __restrict__ g,
                                                     float* __restrict__ beta) {
    int id = blockIdx.x * blockDim.x + threadIdx.x;
    if (id >= S_ * HV_) return;
    int s  = id >> 4;
    int hv = id & 15;
    int hk = hv >> 1;
    int r  = hv & 1;
    float b = ba[s * 32 + hk * 4 + r];
    float a = ba[s * 32 + hk * 4 + 2 + r];
    beta[id] = 1.f / (1.f + expf(-b));
    float x  = a + dt_bias[hv];
    float sp = (x > 20.f) ? x : log1pf(expf(x));
    g[id] = expf(-expf(A_log[hv]) * sp);
}

// ---------------------------------------------------------------------------
// cross-lane reductions: DPP xor1/2/4/8 + ds_swizzle xor16 -> sum over 32-lane group
// ---------------------------------------------------------------------------
template<int CTRL>
__device__ __forceinline__ float dpp_xor(float x) {
    int v = __builtin_amdgcn_update_dpp(0, __float_as_int(x), CTRL, 0xF, 0xF, true);
    return __int_as_float(v);
}
__device__ __forceinline__ float red32(float x) {
    x += dpp_xor<0xB1>(x);   // xor 1
    x += dpp_xor<0x4E>(x);   // xor 2
    x += dpp_xor<0x141>(x);  // xor 4 (row_half_mirror)
    x += dpp_xor<0x140>(x);  // xor 8 (row_mirror)
    x += __int_as_float(__builtin_amdgcn_ds_swizzle(__float_as_int(x), 0x401F)); // xor 16
    return x;
}

// ---------------------------------------------------------------------------
// scal_kernel: per (t,h) scalars {P, W1, beta, g}:
//   C_t = k_t . k_{t-1}  (per hk);  P = -g_t*C_t*beta_t;  W1 = g_t*g_{t-1}
// grid (S_), block 256 = 8 hk x 32 lanes.
// ---------------------------------------------------------------------------
__global__ __launch_bounds__(256) void scal_kernel(const float* __restrict__ kc,
                                                   const float* __restrict__ gbuf,
                                                   const float* __restrict__ bbuf,
                                                   float* __restrict__ scal) {
    const int t  = blockIdx.x;
    const int hk = threadIdx.x >> 5;
    const int s32 = threadIdx.x & 31;

    float c = 0.f;
    if (t > 0) {
        float4 kt = *(const float4*)&kc[((size_t)t * HK_ + hk) * DK_ + s32 * 4];
        float4 kp = *(const float4*)&kc[((size_t)(t - 1) * HK_ + hk) * DK_ + s32 * 4];
        c = fmaf(kt.x, kp.x, 0.f) + kt.y * kp.y + kt.z * kp.z + kt.w * kp.w;
    }
    c = red32(c);

    if (s32 < 2) {
        int h = hk * 2 + s32;
        float gt = gbuf[t * HV_ + h];
        float gp = (t > 0) ? gbuf[(t - 1) * HV_ + h] : 0.f;
        float bt = bbuf[t * HV_ + h];
        float4 o;
        o.x = -gt * c * bt;   // P
        o.y = gt * gp;        // W1
        o.z = bt;             // beta
        o.w = gt;             // g_t
        *(float4*)&scal[((size_t)h * S_ + t) * 4] = o;
    }
}

// ---------------------------------------------------------------------------
// gated delta-rule scan, lookahead form:
//   U_t   = k_t . S_{t-2}          (off critical path, red32)
//   D_t   = fma(P_t, D_{t-1}, Q_t),  Q_t = (v_t - W1_t*U_t)*beta_t   <- 1-op chain
//   S_{t-1} = g_{t-1} S_{t-2} + k_{t-1} D_{t-1}   (updated at iter t)
//   o_{t-1} = q_{t-1} . S_{t-1}    (emitted one iter late)
// grid (DV/8=16, HV=16); block 256 = 4 waves; wave = 32 subs x 2 cols.
// thread rows: {2s, 2s+1, 64+2s, 64+2s+1}  (b64 LDS reads, 2-way = free)
// ---------------------------------------------------------------------------
__global__ __launch_bounds__(256) void scan_kernel(const float* __restrict__ qc,
                                                   const float* __restrict__ kc,
                                                   const float* __restrict__ vc,
                                                   const float* __restrict__ scal,
                                                   float* __restrict__ core) {
    const int h = blockIdx.y, v0 = blockIdx.x * 8;
    const int t = threadIdx.x;
    const int lane = t & 63, w = t >> 6;
    const int sub = lane & 31, cw = lane >> 5;
    const int vloc = w * 2 + cw;
    const int v = v0 + vloc;
    const int hk = h >> 1;

    __shared__ __align__(16) float skq[2][32][256];  // [step][ k(128) | q(128) ]
    __shared__ __align__(16) float sv[2][32][8];
    __shared__ __align__(16) float ssc[2][32][4];    // {P, W1, beta, g}

    auto stage = [&](int buf, int c) {
        int t0 = c * 32;
#pragma unroll
        for (int j = 0; j < 8; ++j) {                // k | q : 1 KB per step
            int st = w * 8 + j;
            int tt = t0 + st;
            const float* src = (lane < 32)
                ? &kc[((size_t)tt * HK_ + hk) * DK_ + lane * 4]
                : &qc[((size_t)tt * HK_ + hk) * DK_ + (lane - 32) * 4];
            gl2lds16(src, &skq[buf][st][0]);
        }
        {                                            // v : 8 steps x 8 cols per wave
            int tt = t0 + w * 8 + (lane >> 3);
            gl2lds4(&vc[((size_t)tt * HV_ + h) * DV_ + v0 + (lane & 7)],
                    &sv[buf][w * 8][0]);
        }
        if (w == 0) {                                // scalars : 128 floats
#pragma unroll
            for (int i = 0; i < 2; ++i)
                gl2lds4(&scal[((size_t)h * S_ + t0) * 4 + i * 64 + lane],
                        ((float*)&ssc[buf][0][0]) + i * 64);
        }
    };

    float S0 = 0.f, S1 = 0.f, S2 = 0.f, S3 = 0.f;
    float4 kp = {0.f, 0.f, 0.f, 0.f};
    float4 qp = {0.f, 0.f, 0.f, 0.f};
    float D = 0.f, gprev = 0.f;

    stage(0, 0);
    __syncthreads();

    for (int c = 0; c < 16; ++c) {
        const int buf = c & 1;
        if (c + 1 < 16) stage(buf ^ 1, c + 1);

        float2 kA[3], kB[3], qA[3], qB[3];
        float vr[3];
        float4 sc[3];
        auto rd = [&](int slot, int j) {
            kA[slot] = *(const float2*)&skq[buf][j][sub * 2];
            kB[slot] = *(const float2*)&skq[buf][j][64 + sub * 2];
            qA[slot] = *(const float2*)&skq[buf][j][128 + sub * 2];
            qB[slot] = *(const float2*)&skq[buf][j][192 + sub * 2];
            vr[slot] = sv[buf][j][vloc];
            sc[slot] = *(const float4*)&ssc[buf][j][0];
        };
        rd(0, 0); rd(1, 1);
#pragma unroll
        for (int j = 0; j < 32; ++j) {
            const int sl = j % 3;
            if (j + 2 < 32) rd((j + 2) % 3, j + 2);
            const float4 s4 = sc[sl];
            // U_t = k_t . S_{t-2}   (S not yet updated)
            float u0 = fmaf(kA[sl].x, S0, kA[sl].y * S1);
            float u1 = fmaf(kB[sl].x, S2, kB[sl].y * S3);
            float U = red32(u0 + u1);
            // S_{t-2} -> S_{t-1}
            S0 = fmaf(kp.x, D, gprev * S0);
            S1 = fmaf(kp.y, D, gprev * S1);
            S2 = fmaf(kp.z, D, gprev * S2);
            S3 = fmaf(kp.w, D, gprev * S3);
            // o_{t-1} = q_{t-1} . S_{t-1}
            float o0 = fmaf(qp.x, S0, qp.y * S1);
            float o1 = fmaf(qp.z, S2, qp.w * S3);
            float om = red32(o0 + o1);
            int tg = c * 32 + j;
            if (sub == 0 && tg > 0)
                core[((size_t)(tg - 1) * HV_ + h) * DV_ + v] = om;
            // D_t = P*D_{t-1} + Q_t
            float Q = fmaf(-s4.y, U, vr[sl]) * s4.z;
            D = fmaf(s4.x, D, Q);
            kp = make_float4(kA[sl].x, kA[sl].y, kB[sl].x, kB[sl].y);
            qp = make_float4(qA[sl].x, qA[sl].y, qB[sl].x, qB[sl].y);
            gprev = s4.w;
        }
        __syncthreads();
    }

    // final: S_510 -> S_511, o_511
    S0 = fmaf(kp.x, D, gprev * S0);
    S1 = fmaf(kp.y, D, gprev * S1);
    S2 = fmaf(kp.z, D, gprev * S2);
    S3 = fmaf(kp.w, D, gprev * S3);
    float o0 = fmaf(qp.x, S0, qp.y * S1);
    float o1 = fmaf(qp.z, S2, qp.w * S3);
    float om = red32(o0 + o1);
    if (sub == 0)
        core[((size_t)(S_ - 1) * HV_ + h) * DV_ + v] = om;
}

// ---------------------------------------------------------------------------
// RMS-norm + silu(z) gate -> bf16 (feeds gemm2 as A)
// ---------------------------------------------------------------------------
__global__ __launch_bounds__(128) void normgate_kernel(const float* __restrict__ core,
                                                       const float* __restrict__ qkvz,
                                                       const float* __restrict__ nw,
                                                       ushort_t* __restrict__ nh) {
    const int s  = blockIdx.x;
    const int hv = blockIdx.y;
    const int d  = threadIdx.x;

    float x = core[((size_t)s * HV_ + hv) * DV_ + d];
    float ss = x * x;
#pragma unroll
    for (int m = 1; m < 64; m <<= 1) ss += __shfl_xor(ss, m);
    __shared__ float red[2];
    int wid = threadIdx.x >> 6;
    if ((threadIdx.x & 63) == 0) red[wid] = ss;
    __syncthreads();
    float var = (red[0] + red[1]) * (1.f / 128.f);
    float rs  = rsqrtf(var + EPS_);

    float z  = qkvz[(size_t)s * QKVZ_N + (hv >> 1) * 768 + 512 + (hv & 1) * 128 + d];
    float sz = z / (1.f + expf(-z));

    float y = x * rs * nw[d] * sz;
    nh[(size_t)s * VAL_DIM_ + hv * DV_ + d] = f2bf(y);
}

// ---------------------------------------------------------------------------
// launch
// ---------------------------------------------------------------------------
extern "C" void kernel_launch(void* const* d_in, const int* in_sizes, int n_in,
                              void* d_out, int out_size, void* d_ws, size_t ws_size,
                              hipStream_t stream) {
    const float* hidden  = (const float*)d_in[0];
    const float* W_qkvz  = (const float*)d_in[1];
    const float* W_ba    = (const float*)d_in[2];
    const float* conv_w  = (const float*)d_in[3];
    const float* dt_bias = (const float*)d_in[4];
    const float* A_log   = (const float*)d_in[5];
    const float* norm_w  = (const float*)d_in[6];
    const float* W_out   = (const float*)d_in[7];
    float* out = (float*)d_out;

    char* w = (char*)d_ws;
    auto alloc = [&](size_t bytes) { char* p = w; w += (bytes + 255) & ~(size_t)255; return p; };

    float*    qkvz = (float*)alloc((size_t)S_ * QKVZ_N * 4);
    float*    ba   = (float*)alloc((size_t)S_ * 32 * 4);
    float*    qc   = (float*)alloc((size_t)S_ * KEY_DIM_ * 4);
    float*    kc   = (float*)alloc((size_t)S_ * KEY_DIM_ * 4);
    float*    vc   = (float*)alloc((size_t)S_ * VAL_DIM_ * 4);
    float*    gbuf = (float*)alloc((size_t)S_ * HV_ * 4);
    float*    bbuf = (float*)alloc((size_t)S_ * HV_ * 4);
    float*    scal = (float*)alloc((size_t)HV_ * S_ * 4 * 4);
    float*    core = (float*)alloc((size_t)S_ * VAL_DIM_ * 4);
    ushort_t* hidh = (ushort_t*)alloc((size_t)S_ * D_ * 2);
    ushort_t* nrmh = (ushort_t*)alloc((size_t)S_ * VAL_DIM_ * 2);
    ushort_t* Wqh  = (ushort_t*)alloc((size_t)D_ * QKVZ_N * 2);
    ushort_t* Woh  = (ushort_t*)alloc((size_t)VAL_DIM_ * D_ * 2);

    // 0a. hidden -> bf16
    convert_bf16<<<dim3((S_ * D_ / 4 + 255) / 256), 256, 0, stream>>>(hidden, hidh, S_ * D_ / 4);
    // 0b. W_qkvz [2048][6144] -> [6144][2048] bf16
    transpose_convert<<<dim3(QKVZ_N / 64, D_ / 64), 256, 0, stream>>>(W_qkvz, Wqh, D_, QKVZ_N);
    // 0c. W_out [2048][2048] -> [2048][2048] bf16 (transposed)
    transpose_convert<<<dim3(D_ / 64, VAL_DIM_ / 64), 256, 0, stream>>>(W_out, Woh, VAL_DIM_, D_);

    // 1. qkvz = hidden @ W_qkvz  (64x128 tiles -> 384 blocks, 2-3/CU overlap)
    gemm_bf16<64, 128, 1, 4><<<dim3(QKVZ_N / 128, S_ / 64), 256, 0, stream>>>(
        hidh, Wqh, qkvz, S_, QKVZ_N, D_);

    // 2. ba
    ba_kernel<<<dim3(S_), 256, 0, stream>>>(hidden, W_ba, ba);

    // 3. conv + silu + l2norm
    conv_kernel<<<dim3(S_, 32), 128, 0, stream>>>(qkvz, conv_w, qc, kc, vc);

    // 4. gating
    gating_kernel<<<dim3((S_ * HV_ + 255) / 256), 256, 0, stream>>>(ba, A_log, dt_bias, gbuf, bbuf);

    // 4b. per-step scalars {P, W1, beta, g}
    scal_kernel<<<dim3(S_), 256, 0, stream>>>(kc, gbuf, bbuf, scal);

    // 5. scan (lookahead, 1-op chain)
    scan_kernel<<<dim3(DV_ / 8, HV_), 256, 0, stream>>>(qc, kc, vc, scal, core);

    // 6. RMS norm + gate -> bf16
    normgate_kernel<<<dim3(S_, HV_), 128, 0, stream>>>(core, qkvz, norm_w, nrmh);

    // 7. out = nrm @ W_out  (64x64 tiles, 256 blocks)
    gemm_bf16<64, 64, 2, 2><<<dim3(D_ / 64, S_ / 64), 256, 0, stream>>>(
        nrmh, Woh, out, S_, D_, VAL_DIM_);
}